// Round 1
// baseline (2736.181 us; speedup 1.0000x reference)
//
#include <hip/hip_runtime.h>
#include <hip/hip_bf16.h>

// Bahdanau additive attention, B=64, S=2048, H=1024 (fp32 in/out).
//   score[b,s] = sum_o v[o] * tanh( (enc[b,s,:]@W_h[o,:]) + (dec[b,:]@W_s[o,:]) )
//   weights = softmax_s(score);  context[b,:] = sum_s weights[b,s]*enc[b,s,:]
// Main GEMM (enc@W_h^T, 275 GFLOP) in bf16 MFMA 16x16x32, fused with tanh+v-dot
// so enc_proj [B,S,H] (512MB) is never materialized.
//
// d_ws layout: [0, 256KB) dec_proj fp32 [64][1024]; [256KB, 256KB+2MB) W_h bf16.
// Requires ws_size >= 2.25 MB.

#define B_ 64
#define S_ 2048
#define H_ 1024
#define BM 64
#define LDA 1032   // 1024 + 8 bf16 pad: row stride 516 dwords -> bank-balanced b128 frag reads

typedef __attribute__((ext_vector_type(8))) short short8;   // 8 bf16 (4 VGPRs)
typedef __attribute__((ext_vector_type(4))) float floatx4;  // MFMA acc

__device__ __forceinline__ short f2bf(float f) {
    union { float f; unsigned u; } c; c.f = f;
    unsigned u = c.u;
    return (short)((u + 0x7FFFu + ((u >> 16) & 1u)) >> 16);  // RTNE
}

// ---------------- dec_proj[b,o] = sum_h dec[b,h] * W_s[o,h] ----------------
__global__ __launch_bounds__(256) void dec_proj_kernel(
        const float* __restrict__ dec, const float* __restrict__ Ws,
        float* __restrict__ dp) {
    __shared__ float sdec[H_];
    const int b = blockIdx.y;
    const int o = blockIdx.x * 256 + threadIdx.x;
    ((float4*)sdec)[threadIdx.x] = ((const float4*)(dec + b * H_))[threadIdx.x];
    __syncthreads();
    const float4* wr = (const float4*)(Ws + (size_t)o * H_);
    float acc = 0.f;
#pragma unroll 4
    for (int i = 0; i < H_ / 4; ++i) {
        float4 wv = wr[i];
        acc += sdec[4*i+0]*wv.x + sdec[4*i+1]*wv.y + sdec[4*i+2]*wv.z + sdec[4*i+3]*wv.w;
    }
    dp[b * H_ + o] = acc;
}

// ---------------- W_h fp32 -> bf16 ----------------
__global__ __launch_bounds__(256) void cvt_wh_kernel(
        const float* __restrict__ Wh, short* __restrict__ Wbf) {
    const int i = blockIdx.x * 256 + threadIdx.x;   // one float4 per thread
    float4 f = ((const float4*)Wh)[i];
    *(short4*)&Wbf[i * 4] = make_short4(f2bf(f.x), f2bf(f.y), f2bf(f.z), f2bf(f.w));
}

// ---------------- fused enc@W_h^T + dp -> tanh -> dot v -> score ----------------
// Block: 4 waves, 64 rows (one b, 64 consecutive s). A (enc tile, full K) LDS-resident
// in bf16: staged once, then a barrier-free K*N loop. Wave w owns rows [16w,16w+16);
// per pass p covers cols [256p, 256p+256) as 16 n-frags; B-frags loaded straight from
// global bf16 W (16B contiguous per lane), identical across waves -> L1 reuse.
__global__ __launch_bounds__(256, 1) void score_kernel(
        const float* __restrict__ enc, const short* __restrict__ Wbf,
        const float* __restrict__ dp, const float* __restrict__ v,
        float* __restrict__ score) {
    __shared__ short As[BM * LDA];   // 132096 B

    const int tid  = threadIdx.x;
    const int wave = tid >> 6;
    const int lane = tid & 63;
    const int l15  = lane & 15;
    const int quad = lane >> 4;

    const int b  = blockIdx.x >> 5;          // 32 row-tiles per batch
    const int s0 = (blockIdx.x & 31) * BM;
    const long rowBase = (long)b * S_ + s0;

    // stage enc tile fp32 -> bf16 (64 rows x 1024), coalesced: one row per iter
    const float4* encB = (const float4*)(enc + rowBase * H_);
#pragma unroll 4
    for (int r = 0; r < BM; ++r) {
        float4 f = encB[r * (H_ / 4) + tid];
        *(short4*)&As[r * LDA + tid * 4] =
            make_short4(f2bf(f.x), f2bf(f.y), f2bf(f.z), f2bf(f.w));
    }
    __syncthreads();   // the only barrier in this kernel

    // A-frag: A[m=l15][k=quad*8+j] from row (16*wave + l15)
    const short* aBase = As + (wave * 16 + l15) * LDA + quad * 8;

    float rp[4] = {0.f, 0.f, 0.f, 0.f};  // per-(quad,reg) row partial of score

    for (int p = 0; p < 4; ++p) {
        floatx4 acc[16];
#pragma unroll
        for (int nt = 0; nt < 16; ++nt) acc[nt] = (floatx4){0.f, 0.f, 0.f, 0.f};

        const int colBase = p * 256 + l15;
        const short* bp[16];
#pragma unroll
        for (int nt = 0; nt < 16; ++nt)
            bp[nt] = Wbf + (size_t)(colBase + nt * 16) * H_ + quad * 8;

#pragma unroll 2
        for (int kt = 0; kt < 32; ++kt) {
            short8 af = *(const short8*)(aBase + kt * 32);
            short8 bf[16];
#pragma unroll
            for (int nt = 0; nt < 16; ++nt)
                bf[nt] = *(const short8*)(bp[nt] + kt * 32);
#pragma unroll
            for (int nt = 0; nt < 16; ++nt)
                acc[nt] = __builtin_amdgcn_mfma_f32_16x16x32_bf16(af, bf[nt], acc[nt], 0, 0, 0);
        }

        // epilogue: proj + dp -> tanh -> * v, accumulate per row
#pragma unroll
        for (int nt = 0; nt < 16; ++nt) {
            const int o = p * 256 + nt * 16 + l15;
            const float dpv = dp[b * H_ + o];
            const float vv  = v[o];
#pragma unroll
            for (int r = 0; r < 4; ++r) {
                float x = acc[nt][r] + dpv;            // D[row=quad*4+r][col=l15]
                x = fminf(10.f, fmaxf(-10.f, x));
                float t = __expf(x + x);               // e^(2x)
                float e = 1.f - 2.f * __builtin_amdgcn_rcpf(t + 1.f);
                rp[r] += e * vv;
            }
        }
    }

    // reduce across the 16 lanes of each quad (xor 1,2,4,8 stays in-quad), write score
#pragma unroll
    for (int r = 0; r < 4; ++r) {
        float sum = rp[r];
        sum += __shfl_xor(sum, 1, 64);
        sum += __shfl_xor(sum, 2, 64);
        sum += __shfl_xor(sum, 4, 64);
        sum += __shfl_xor(sum, 8, 64);
        if (l15 == 0)
            score[b * S_ + s0 + wave * 16 + quad * 4 + r] = sum;
    }
}

// ---------------- softmax over S in-place (d_out weights region) + zero context ----------------
__global__ __launch_bounds__(256) void softmax_kernel(float* __restrict__ out) {
    const int b = blockIdx.x;
    const int tid = threadIdx.x;
    float* sc = out + B_ * H_ + b * S_;

    // zero this batch's context row; context_kernel accumulates with atomics
    ((float4*)(out + b * H_))[tid] = make_float4(0.f, 0.f, 0.f, 0.f);

    float xs[8];
    float m = -1e30f;
#pragma unroll
    for (int i = 0; i < 8; ++i) { xs[i] = sc[tid + i * 256]; m = fmaxf(m, xs[i]); }
#pragma unroll
    for (int off = 32; off > 0; off >>= 1) m = fmaxf(m, __shfl_xor(m, off, 64));
    __shared__ float redm[4];
    const int wv = tid >> 6;
    if ((tid & 63) == 0) redm[wv] = m;
    __syncthreads();
    m = fmaxf(fmaxf(redm[0], redm[1]), fmaxf(redm[2], redm[3]));

    float s = 0.f;
#pragma unroll
    for (int i = 0; i < 8; ++i) { xs[i] = __expf(xs[i] - m); s += xs[i]; }
#pragma unroll
    for (int off = 32; off > 0; off >>= 1) s += __shfl_xor(s, off, 64);
    __shared__ float reds[4];
    if ((tid & 63) == 0) reds[wv] = s;
    __syncthreads();
    s = reds[0] + reds[1] + reds[2] + reds[3];

    const float inv = 1.f / s;
#pragma unroll
    for (int i = 0; i < 8; ++i) sc[tid + i * 256] = xs[i] * inv;
}

// ---------------- context[b,h] = sum_s weights[b,s] * enc[b,s,h] ----------------
// grid (64, 8): 8 s-chunks of 256 per batch, atomicAdd partials (context pre-zeroed).
__global__ __launch_bounds__(256) void context_kernel(
        const float* __restrict__ enc, const float* __restrict__ wts,
        float* __restrict__ ctx) {
    const int b    = blockIdx.x;
    const int scnk = blockIdx.y;
    const int t    = threadIdx.x;
    const float* w  = wts + b * S_ + scnk * 256;
    const float4* e = (const float4*)(enc + ((long)b * S_ + scnk * 256) * H_);
    float4 acc = make_float4(0.f, 0.f, 0.f, 0.f);
#pragma unroll 4
    for (int s = 0; s < 256; ++s) {
        const float ww = w[s];                  // wave-uniform -> scalar load
        const float4 ev = e[s * (H_ / 4) + t];  // 4KB contiguous per iter
        acc.x = fmaf(ww, ev.x, acc.x);
        acc.y = fmaf(ww, ev.y, acc.y);
        acc.z = fmaf(ww, ev.z, acc.z);
        acc.w = fmaf(ww, ev.w, acc.w);
    }
    float* c = ctx + b * H_ + t * 4;
    atomicAdd(c + 0, acc.x);
    atomicAdd(c + 1, acc.y);
    atomicAdd(c + 2, acc.z);
    atomicAdd(c + 3, acc.w);
}

extern "C" void kernel_launch(void* const* d_in, const int* in_sizes, int n_in,
                              void* d_out, int out_size, void* d_ws, size_t ws_size,
                              hipStream_t stream) {
    const float* dec = (const float*)d_in[0];   // [64,1,1024]
    const float* enc = (const float*)d_in[1];   // [64,2048,1024]
    const float* Wh  = (const float*)d_in[2];   // [1024,1024]
    const float* Ws  = (const float*)d_in[3];   // [1024,1024]
    const float* v   = (const float*)d_in[4];   // [1024]

    float* out = (float*)d_out;
    float* ctx = out;                 // [64*1024] context
    float* wts = out + B_ * H_;       // [64*2048] scores -> weights (in place)

    float* dp  = (float*)d_ws;                                    // 256 KB
    short* Wbf = (short*)((char*)d_ws + (size_t)B_ * H_ * 4);     // 2 MB bf16
    (void)in_sizes; (void)n_in; (void)out_size; (void)ws_size;

    dec_proj_kernel<<<dim3(H_ / 256, B_), 256, 0, stream>>>(dec, Ws, dp);
    cvt_wh_kernel<<<(H_ * H_ / 4) / 256, 256, 0, stream>>>(Wh, Wbf);
    score_kernel<<<(B_ * S_) / BM, 256, 0, stream>>>(enc, Wbf, dp, v, wts);
    softmax_kernel<<<B_, 256, 0, stream>>>(out);
    context_kernel<<<dim3(B_, S_ / 256), 256, 0, stream>>>(enc, wts, ctx);
}

// Round 2
// 1277.124 us; speedup vs baseline: 2.1425x; 2.1425x over previous
//
#include <hip/hip_runtime.h>
#include <hip/hip_bf16.h>

// Bahdanau additive attention, B=64, S=2048, H=1024 (fp32 in/out).
//   score[b,s] = sum_o v[o] * tanh( (enc[b,s,:].W_h[o,:]) + dp[b,o] )
//   weights = softmax_s(score);  context[b,:] = sum_s weights[b,s]*enc[b,s,:]
//
// R2: m97-style 128x128 MFMA GEMM (M=B*S=131072, N=H=1024, K=H=1024), BK=64,
// 2x2 waves x 4x4 frags, B via global_load_lds(16B) with XOR chunk swizzle,
// A fp32->bf16 converted through VGPRs into padded LDS. Fused epilogue does
// +dp, tanh, *v, reduces over this block's 128 cols, atomicAdds partial into
// pre-zeroed score. 8 N-blocks per M-tile are dispatch-adjacent for L3 reuse.
//
// d_ws: [0,256KB) dec_proj fp32 [64][1024]; [256KB,256KB+2MB) W_h bf16.

#define B_ 64
#define S_ 2048
#define H_ 1024
#define AST 72   // A-tile LDS stride in bf16 (64 + 8 pad -> bank-uniform b128 reads)

typedef __attribute__((ext_vector_type(8))) short short8;   // 8 bf16
typedef __attribute__((ext_vector_type(4))) float floatx4;  // MFMA acc

__device__ __forceinline__ short f2bf(float f) {
    unsigned u = __float_as_uint(f);
    return (short)((u + 0x7FFFu + ((u >> 16) & 1u)) >> 16);  // RTNE
}
__device__ __forceinline__ unsigned pk2bf(float a, float b) {  // low=a, high=b
    unsigned ua = __float_as_uint(a), ub = __float_as_uint(b);
    ua = (ua + 0x7FFFu + ((ua >> 16) & 1u)) >> 16;
    ub = (ub + 0x7FFFu + ((ub >> 16) & 1u)) & 0xFFFF0000u;
    return ua | ub;
}
__device__ __forceinline__ void gload_lds16(const void* g, void* l) {
    __builtin_amdgcn_global_load_lds(
        (const __attribute__((address_space(1))) unsigned*)g,
        (__attribute__((address_space(3))) unsigned*)l, 16, 0, 0);
}

// ---------------- zero the score region (atomicAdd target) ----------------
__global__ __launch_bounds__(256) void zero_score_kernel(float* __restrict__ sc) {
    ((float4*)sc)[blockIdx.x * 256 + threadIdx.x] = make_float4(0.f, 0.f, 0.f, 0.f);
}

// ---------------- dec_proj[b,o] = sum_h dec[b,h] * W_s[o,h] ----------------
__global__ __launch_bounds__(256) void dec_proj_kernel(
        const float* __restrict__ dec, const float* __restrict__ Ws,
        float* __restrict__ dp) {
    __shared__ float sdec[H_];
    const int b = blockIdx.y;
    const int o = blockIdx.x * 256 + threadIdx.x;
    ((float4*)sdec)[threadIdx.x] = ((const float4*)(dec + b * H_))[threadIdx.x];
    __syncthreads();
    const float4* wr = (const float4*)(Ws + (size_t)o * H_);
    float acc = 0.f;
#pragma unroll 4
    for (int i = 0; i < H_ / 4; ++i) {
        float4 wv = wr[i];
        acc += sdec[4*i+0]*wv.x + sdec[4*i+1]*wv.y + sdec[4*i+2]*wv.z + sdec[4*i+3]*wv.w;
    }
    dp[b * H_ + o] = acc;
}

// ---------------- W_h fp32 -> bf16 ----------------
__global__ __launch_bounds__(256) void cvt_wh_kernel(
        const float* __restrict__ Wh, short* __restrict__ Wbf) {
    const int i = blockIdx.x * 256 + threadIdx.x;
    float4 f = ((const float4*)Wh)[i];
    *(short4*)&Wbf[i * 4] = make_short4(f2bf(f.x), f2bf(f.y), f2bf(f.z), f2bf(f.w));
}

// ---------------- fused score GEMM ----------------
// grid.x = (M/128)*(N/128) = 1024*8; mtile = bid>>3, nb = bid&7 (nb-siblings
// adjacent -> concurrent A-tile reads hit L3; nb<->XCD keeps W slice in L2).
__global__ __launch_bounds__(256, 3) void score_kernel(
        const float* __restrict__ enc, const short* __restrict__ Wbf,
        const float* __restrict__ dp, const float* __restrict__ v,
        float* __restrict__ score) {
    __shared__ short As[128 * AST];   // 18432 B, As[m][k] = bf16(enc[m0+m][k0+k])
    __shared__ short Bs[128 * 64];    // 16384 B, Bs[n][c8] holds global chunk c8^(n&7)

    const int tid  = threadIdx.x;
    const int wave = tid >> 6;
    const int lane = tid & 63;
    const int l15  = lane & 15;
    const int quad = lane >> 4;
    const int wy   = wave & 1;        // m-half
    const int wx   = wave >> 1;       // n-half

    const int mtile = blockIdx.x >> 3;
    const int nb    = blockIdx.x & 7;
    const int m0    = mtile * 128;    // global row index (b*S + s)
    const int n0    = nb * 128;
    const int b     = m0 >> 11;       // 16 M-tiles per batch

    floatx4 acc[4][4];
#pragma unroll
    for (int i = 0; i < 4; ++i)
#pragma unroll
        for (int j = 0; j < 4; ++j) acc[i][j] = (floatx4){0.f, 0.f, 0.f, 0.f};

    // frag read bases
    const short* aLds = As + (wy * 64 + l15) * AST;    // + i*16*AST + kt*32 + quad*8
    const short* bLds = Bs + (wx * 64 + l15) * 64;     // + j*16*64 + swz-chunk*8
    const int swz = l15 & 7;

    // staging decomposition (loop-invariant parts)
    const int nrow = ((0 * 256 + tid) >> 3);           // per r: (r*256+tid)>>3 = r*32 + tid>>3
    const int bc   = tid & 7;                          // B chunk id within row
    (void)nrow;

    for (int k0 = 0; k0 < H_; k0 += 64) {
        // ---- B tile: 128 rows x 64 k bf16 via async 16B direct-to-LDS ----
#pragma unroll
        for (int r = 0; r < 4; ++r) {
            const int n = r * 32 + (tid >> 3);         // (r*256+tid)>>3
            const int g = bc ^ (n & 7);                // XOR chunk swizzle (global side)
            const short* gp = Wbf + (size_t)(n0 + n) * H_ + k0 + g * 8;
            // wave-uniform LDS base: lanes of wave w, round r land at [(r*256+w*64)*8 ..]
            gload_lds16(gp, (void*)(Bs + (r * 256 + wave * 64) * 8));
        }
        // ---- A tile: 128 rows x 64 k fp32 -> bf16 -> LDS (stride AST) ----
#pragma unroll
        for (int i = 0; i < 4; ++i) {
            const int La = i * 256 + tid;              // 8-float chunk id
            const int m  = La >> 3;
            const int c8 = La & 7;
            const float4* gp = (const float4*)(enc + (size_t)(m0 + m) * H_ + k0 + c8 * 8);
            float4 f0 = gp[0], f1 = gp[1];
            union { short8 s; unsigned u[4]; } cv;
            cv.u[0] = pk2bf(f0.x, f0.y);
            cv.u[1] = pk2bf(f0.z, f0.w);
            cv.u[2] = pk2bf(f1.x, f1.y);
            cv.u[3] = pk2bf(f1.z, f1.w);
            *(short8*)&As[m * AST + c8 * 8] = cv.s;
        }
        __syncthreads();   // drains vmcnt (async B) + lgkm (A writes)

        // ---- compute: 2 kt x (4 a-frag + 4 b-frag reads, 16 MFMA) ----
#pragma unroll
        for (int kt = 0; kt < 2; ++kt) {
            short8 af[4], bf[4];
#pragma unroll
            for (int i = 0; i < 4; ++i)
                af[i] = *(const short8*)(aLds + i * 16 * AST + kt * 32 + quad * 8);
#pragma unroll
            for (int j = 0; j < 4; ++j)
                bf[j] = *(const short8*)(bLds + j * 16 * 64 + (((kt * 4 + quad) ^ swz) * 8));
#pragma unroll
            for (int i = 0; i < 4; ++i)
#pragma unroll
                for (int j = 0; j < 4; ++j)
                    acc[i][j] = __builtin_amdgcn_mfma_f32_16x16x32_bf16(af[i], bf[j], acc[i][j], 0, 0, 0);
        }
        __syncthreads();   // protect LDS before next stage
    }

    // ---- fused epilogue: +dp, tanh, *v, reduce over block's 128 cols ----
    float part[4][4];
#pragma unroll
    for (int i = 0; i < 4; ++i)
#pragma unroll
        for (int r = 0; r < 4; ++r) part[i][r] = 0.f;

#pragma unroll
    for (int j = 0; j < 4; ++j) {
        const int o = n0 + wx * 64 + j * 16 + l15;
        const float dpv = dp[b * H_ + o];
        const float vv  = v[o];
#pragma unroll
        for (int i = 0; i < 4; ++i)
#pragma unroll
            for (int r = 0; r < 4; ++r) {
                float x = acc[i][j][r] + dpv;          // D[row=quad*4+r][col=l15]
                x = fminf(10.f, fmaxf(-10.f, x));
                float e = __expf(x + x);               // e^(2x)
                float t = 1.f - 2.f * __builtin_amdgcn_rcpf(e + 1.f);
                part[i][r] += t * vv;
            }
    }
#pragma unroll
    for (int i = 0; i < 4; ++i)
#pragma unroll
        for (int r = 0; r < 4; ++r) {
            float s = part[i][r];
            s += __shfl_xor(s, 1, 64);
            s += __shfl_xor(s, 2, 64);
            s += __shfl_xor(s, 4, 64);
            s += __shfl_xor(s, 8, 64);
            if (l15 == 0)   // 4 lanes (quad) hold rows quad*4+r of frag i
                atomicAdd(&score[m0 + wy * 64 + i * 16 + quad * 4 + r], s);
        }
}

// ---------------- softmax over S in-place + zero context ----------------
__global__ __launch_bounds__(256) void softmax_kernel(float* __restrict__ out) {
    const int b = blockIdx.x;
    const int tid = threadIdx.x;
    float* sc = out + B_ * H_ + b * S_;

    ((float4*)(out + b * H_))[tid] = make_float4(0.f, 0.f, 0.f, 0.f);

    float xs[8];
    float m = -1e30f;
#pragma unroll
    for (int i = 0; i < 8; ++i) { xs[i] = sc[tid + i * 256]; m = fmaxf(m, xs[i]); }
#pragma unroll
    for (int off = 32; off > 0; off >>= 1) m = fmaxf(m, __shfl_xor(m, off, 64));
    __shared__ float redm[4];
    const int wv = tid >> 6;
    if ((tid & 63) == 0) redm[wv] = m;
    __syncthreads();
    m = fmaxf(fmaxf(redm[0], redm[1]), fmaxf(redm[2], redm[3]));

    float s = 0.f;
#pragma unroll
    for (int i = 0; i < 8; ++i) { xs[i] = __expf(xs[i] - m); s += xs[i]; }
#pragma unroll
    for (int off = 32; off > 0; off >>= 1) s += __shfl_xor(s, off, 64);
    __shared__ float reds[4];
    if ((tid & 63) == 0) reds[wv] = s;
    __syncthreads();
    s = reds[0] + reds[1] + reds[2] + reds[3];

    const float inv = 1.f / s;
#pragma unroll
    for (int i = 0; i < 8; ++i) sc[tid + i * 256] = xs[i] * inv;
}

// ---------------- context[b,h] = sum_s weights[b,s] * enc[b,s,h] ----------------
__global__ __launch_bounds__(256) void context_kernel(
        const float* __restrict__ enc, const float* __restrict__ wts,
        float* __restrict__ ctx) {
    const int b    = blockIdx.x;
    const int scnk = blockIdx.y;
    const int t    = threadIdx.x;
    const float* w  = wts + b * S_ + scnk * 256;
    const float4* e = (const float4*)(enc + ((long)b * S_ + scnk * 256) * H_);
    float4 acc = make_float4(0.f, 0.f, 0.f, 0.f);
#pragma unroll 4
    for (int s = 0; s < 256; ++s) {
        const float ww = w[s];
        const float4 ev = e[s * (H_ / 4) + t];
        acc.x = fmaf(ww, ev.x, acc.x);
        acc.y = fmaf(ww, ev.y, acc.y);
        acc.z = fmaf(ww, ev.z, acc.z);
        acc.w = fmaf(ww, ev.w, acc.w);
    }
    float* c = ctx + b * H_ + t * 4;
    atomicAdd(c + 0, acc.x);
    atomicAdd(c + 1, acc.y);
    atomicAdd(c + 2, acc.z);
    atomicAdd(c + 3, acc.w);
}

extern "C" void kernel_launch(void* const* d_in, const int* in_sizes, int n_in,
                              void* d_out, int out_size, void* d_ws, size_t ws_size,
                              hipStream_t stream) {
    const float* dec = (const float*)d_in[0];   // [64,1,1024]
    const float* enc = (const float*)d_in[1];   // [64,2048,1024]
    const float* Wh  = (const float*)d_in[2];   // [1024,1024]
    const float* Ws  = (const float*)d_in[3];   // [1024,1024]
    const float* v   = (const float*)d_in[4];   // [1024]

    float* out = (float*)d_out;
    float* ctx = out;                 // [64*1024] context
    float* wts = out + B_ * H_;       // [64*2048] scores -> weights (in place)

    float* dp  = (float*)d_ws;                                 // 256 KB
    short* Wbf = (short*)((char*)d_ws + (size_t)B_ * H_ * 4);  // 2 MB bf16
    (void)in_sizes; (void)n_in; (void)out_size; (void)ws_size;

    zero_score_kernel<<<(B_ * S_ / 4) / 256, 256, 0, stream>>>(wts);
    dec_proj_kernel<<<dim3(H_ / 256, B_), 256, 0, stream>>>(dec, Ws, dp);
    cvt_wh_kernel<<<(H_ * H_ / 4) / 256, 256, 0, stream>>>(Wh, Wbf);
    score_kernel<<<(B_ * S_ / 128) * (H_ / 128), 256, 0, stream>>>(enc, Wbf, dp, v, wts);
    softmax_kernel<<<B_, 256, 0, stream>>>(out);
    context_kernel<<<dim3(B_, S_ / 256), 256, 0, stream>>>(enc, wts, ctx);
}